// Round 8
// baseline (110.081 us; speedup 1.0000x reference)
//
#include <hip/hip_runtime.h>

#define TAU 3.0f
#define FIX 0.2f
#define NPED 1024              // N per batch (reference setup)
#define PEDS_PER_BLOCK 256
#define BLOCK 512
#define GROUPS (BLOCK / 8)                      // 64 peds per pass
#define PASSES (PEDS_PER_BLOCK / GROUPS)        // 4

// DIAGNOSTIC ROUND: exact R2/R5 structure (best known, ~21us) with a runtime
// `reps` loop so the dispatch exceeds the harness's ~41us fill kernels and
// shows up in the top-5 rocprof table with real counters. Each rep re-reads
// the streams and re-writes identical output -> correctness unchanged.
__global__ __launch_bounds__(BLOCK) void rvo_kernel(
    const float* __restrict__ p_cur,     // (B,N,2)
    const float* __restrict__ v_cur,     // (B,N,2)
    const float* __restrict__ v_desire,  // (B,N,2)
    const int*   __restrict__ near_idx,  // (B,N,32)
    const float* __restrict__ mask_arr,  // (B,N,32)
    const int*   __restrict__ cth,       // scalar
    float*       __restrict__ out,       // (B,N,2)
    int N, int reps)
{
    __shared__ float4 table[NPED];

    const int tid    = threadIdx.x;
    const int bpb    = N / PEDS_PER_BLOCK;          // blocks per batch = 4
    const int batch  = blockIdx.x / bpb;
    const int pbase  = (blockIdx.x % bpb) * PEDS_PER_BLOCK;

    // ---- stage packed (p,v) table for this batch: coalesced float2 reads ----
    const float2* pb2 = (const float2*)(p_cur) + (size_t)batch * N;
    const float2* vb2 = (const float2*)(v_cur) + (size_t)batch * N;
    #pragma unroll
    for (int n = tid; n < NPED; n += BLOCK) {
        float2 pp = pb2[n];
        float2 vv = vb2[n];
        table[n] = make_float4(pp.x, pp.y, vv.x, vv.y);
    }
    __syncthreads();

    const float thr2 = (float)cth[0] * (float)cth[0];

    const int sub  = tid & 7;        // which 4-neighbor chunk (k = sub*4..sub*4+3)
    const int pgrp = tid >> 3;       // 0..63: pedestrian within pass

    for (int r = 0; r < reps; ++r) {
        #pragma unroll
        for (int pass = 0; pass < PASSES; ++pass) {
            const int ped  = pbase + pass * GROUPS + pgrp;
            const size_t pair = (size_t)batch * N + ped;

            // broadcast per-ped scalars (8 lanes same address)
            const float4 self = table[ped];
            const float2 vd   = ((const float2*)v_desire)[pair];
            const float px = self.x, py = self.y;
            const float vdx = vd.x, vdy = vd.y;

            // coalesced vector loads: 32 idx/mask per ped = 8 int4/float4
            const int4   i4 = ((const int4*)near_idx)[pair * 8 + sub];
            const float4 m4 = ((const float4*)mask_arr)[pair * 8 + sub];
            const int   idxs[4] = {i4.x, i4.y, i4.z, i4.w};
            const float ms[4]   = {m4.x, m4.y, m4.z, m4.w};

            float nx = 0.0f, ny = 0.0f;
            #pragma unroll
            for (int j = 0; j < 4; ++j) {
                const float4 nb = table[idxs[j]];    // LDS gather, ds_read_b128
                const float m = ms[j];
                const float rpx = fmaf(-m, nb.x, px);
                const float rpy = fmaf(-m, nb.y, py);
                const float rvx = fmaf(-m, nb.z, vdx);
                const float rvy = fmaf(-m, nb.w, vdy);

                const float dpv = fmaf(rpx, rvx, rpy * rvy);
                const float dvv = fmaf(rvx, rvx, fmaf(rvy, rvy, 2e-6f));
                float t = dpv * __builtin_amdgcn_rcpf(dvv);
                t = fminf(fmaxf(t, 0.0f), TAU);

                const float cx = fmaf(t, rvx, rpx);
                const float cy = fmaf(t, rvy, rpy);
                const float md2 = fmaf(cx, cx, cy * cy);

                const float s = fmaf(rpx, rpx, rpy * rpy);
                // s>0 guard: self-neighbor (s==0) contributes exactly 0
                const float sel0 = (s > 0.0f) ? __builtin_amdgcn_rsqf(s) : 0.0f;
                const float w    = (md2 < thr2) ? m : 0.0f;  // m in {0,1}
                const float sel  = sel0 * w;
                nx = fmaf(-rpy, sel, nx);
                ny = fmaf( rpx, sel, ny);
            }

            #pragma unroll
            for (int d = 4; d > 0; d >>= 1) {
                nx += __shfl_down(nx, d, 8);
                ny += __shfl_down(ny, d, 8);
            }

            if (sub == 0) {
                ((float2*)out)[pair] = make_float2(fmaf(nx, FIX, vdx),
                                                   fmaf(ny, FIX, vdy));
            }
        }
    }
}

extern "C" void kernel_launch(void* const* d_in, const int* in_sizes, int n_in,
                              void* d_out, int out_size, void* d_ws, size_t ws_size,
                              hipStream_t stream) {
    const float* p_cur    = (const float*)d_in[0];
    const float* v_cur    = (const float*)d_in[1];
    const float* v_desire = (const float*)d_in[2];
    const int*   near_idx = (const int*)d_in[3];
    const float* mask_arr = (const float*)d_in[4];
    const int*   cth      = (const int*)d_in[5];
    float*       out      = (float*)d_out;

    const int N  = NPED;
    const int BN = in_sizes[0] / 2;          // B*N pedestrians
    dim3 block(BLOCK);
    dim3 grid(BN / PEDS_PER_BLOCK);          // 1024 blocks for B=256
    rvo_kernel<<<grid, block, 0, stream>>>(p_cur, v_cur, v_desire, near_idx,
                                           mask_arr, cth, out, N, /*reps=*/3);
}